// Round 12
// baseline (76.150 us; speedup 1.0000x reference)
//
#include <hip/hip_runtime.h>
#include <hip/hip_bf16.h>

// Problem shape (fixed by setup_inputs): B=8, Q=2048 -> N=16384 rows,
// D=1024, Dp=256, K=2048 prototypes.
#define N_ROWS 16384
#define DIM    1024
#define DP     256
#define NPROTO 2048

typedef float f32x4 __attribute__((ext_vector_type(4)));
typedef short s16x8 __attribute__((ext_vector_type(8)));
typedef short s16x4 __attribute__((ext_vector_type(4)));

__device__ __forceinline__ unsigned short f2bf(float f) {
  __hip_bfloat16 h = __float2bfloat16(f);   // RNE
  return __builtin_bit_cast(unsigned short, h);
}

// LDS-only barrier (no vmcnt drain; global prefetches stay in flight).
__device__ __forceinline__ void lds_barrier() {
  asm volatile("s_waitcnt lgkmcnt(0)" ::: "memory");
  __builtin_amdgcn_s_barrier();
}

// ---- prep: build FRAGMENT-ORDER operands ----
// projT_sw[cg][kb][lane][8]: cg in [0,16), kb in [0,32);
//   lane's 8 bf16 = proj[kb*32+(lane>>4)*8+j][cg*16+(lane&15)].
// Pb_sw[pgrp][kb][lane][8]: pgrp in [0,128), kb in [0,8);
//   lane's 8 bf16 = proto[pgrp*16+(lane&15)][kb*32+(lane>>4)*8+j].
// A wave's MFMA B-fragment load is then base + lane*16B: one coalesced 1KB read.
__global__ void k_prep(const float* __restrict__ proj,
                       const float* __restrict__ P,
                       unsigned short* __restrict__ projT_sw,
                       unsigned short* __restrict__ Pb_sw,
                       float* __restrict__ pp) {
  int b = blockIdx.x;
  int t = threadIdx.x;
  if (b < 128) {                      // projT_sw: 32768 16B chunks
    int q    = b * 256 + t;
    int lane = q & 63, kb = (q >> 6) & 31, cg = q >> 11;
    int c  = cg * 16 + (lane & 15);
    int k0 = kb * 32 + (lane >> 4) * 8;
    s16x8 v;
#pragma unroll
    for (int j = 0; j < 8; ++j)
      v[j] = (short)f2bf(proj[(size_t)(k0 + j) * DP + c]);
    *(s16x8*)(projT_sw + (size_t)q * 8) = v;
  } else if (b < 384) {               // Pb_sw: 65536 16B chunks
    int q    = (b - 128) * 256 + t;
    int lane = q & 63, kb = (q >> 6) & 7, pg = q >> 9;
    const float* src = P + (size_t)(pg * 16 + (lane & 15)) * DP +
                       kb * 32 + (lane >> 4) * 8;
    s16x8 v;
#pragma unroll
    for (int j = 0; j < 8; ++j) v[j] = (short)f2bf(src[j]);
    *(s16x8*)(Pb_sw + (size_t)q * 8) = v;
  } else {                            // pp: one block per proto
    int k = b - 384;
    float v = P[(size_t)k * DP + t];
    float s = v * v;
#pragma unroll
    for (int o = 1; o < 64; o <<= 1) s += __shfl_xor(s, o, 64);
    __shared__ float ws4[4];
    if ((t & 63) == 0) ws4[t >> 6] = s;
    __syncthreads();
    if (t == 0) pp[k] = ws4[0] + ws4[1] + ws4[2] + ws4[3];
  }
}

// ---- G1: Zb_sw = normalize_rows((X - mean) @ proj), FRAGMENT ORDER ----
// 32 rows/block, 512 threads = 8 waves, grid 512 -> 2 blocks/CU.
// R11 phase-1 pipeline (LDS-staged X, 2-deep prefetch, lds_barrier; B
// reg-direct coalesced from projT_sw) + handoff + coalesced frag store:
// Zb_sw[bid*16 + f][lane][8], f = rg*8+kb (rg=row/16 in tile, kb=k/32).
__global__ __launch_bounds__(512, 4)
void k_g1(const float* __restrict__ X, const float* __restrict__ mean,
          const unsigned short* __restrict__ projT_sw,
          unsigned short* __restrict__ Zb_sw) {
  __shared__ __align__(16) unsigned short Zs[32][264];   // 16896 B
  __shared__ __align__(16) unsigned short As[2][32][72]; //  9216 B
  __shared__ __align__(16) float mean_s[DIM];            //  4096 B
  __shared__ float rowsq[8][32];                         //  1024 B
  __shared__ float invs[32];                             //   128 B

  const int tid  = threadIdx.x;
  const int lane = tid & 63;
  const int wv   = tid >> 6;        // wave id 0..7
  const int l15  = lane & 15;
  const int lhi  = lane >> 4;
  const int rb   = blockIdx.x * 32;

  if (tid < 256)
    *(f32x4*)&mean_s[tid * 4] = *(const f32x4*)(mean + tid * 4);
  __syncthreads();

  const int arow = tid >> 4;             // [0,32)
  const int ach  = (tid & 15) * 4;
  const float* xbase = X + (size_t)(rb + arow) * DIM + ach;
  const unsigned short* pj_base =
      projT_sw + (size_t)(wv * 2) * 32 * 64 * 8 + (size_t)lane * 8;

  f32x4 acc[2][2];
#pragma unroll
  for (int mf = 0; mf < 2; ++mf)
#pragma unroll
    for (int cg = 0; cg < 2; ++cg) acc[mf][cg] = (f32x4)0.0f;

  f32x4 xA, xB;
  s16x8 bfA[4], bfB[4];   // [cgi*2+kk]

#define P1X(XR, T) { XR = *(const f32x4*)(xbase + (T) * 64); }
#define P1B(REGS, T)                                                         \
  {                                                                          \
    _Pragma("unroll")                                                        \
    for (int cgi = 0; cgi < 2; ++cgi)                                        \
      _Pragma("unroll")                                                      \
      for (int kk = 0; kk < 2; ++kk)                                         \
        REGS[cgi * 2 + kk] = *(const s16x8*)(pj_base +                       \
            (size_t)(cgi * 32 + (T) * 2 + kk) * 512);                        \
  }
#define P1W(CUR, XR, T)                                                      \
  {                                                                          \
    f32x4 m0 = *(const f32x4*)&mean_s[(T) * 64 + ach];                       \
    f32x4 c0 = XR - m0;                                                      \
    s16x4 v;                                                                 \
    v[0] = (short)f2bf(c0[0]); v[1] = (short)f2bf(c0[1]);                    \
    v[2] = (short)f2bf(c0[2]); v[3] = (short)f2bf(c0[3]);                    \
    *(s16x4*)(&As[CUR][arow][ach]) = v;                                      \
  }
#define P1C(CUR, BF)                                                         \
  {                                                                          \
    s16x8 a[2][2];                                                           \
    _Pragma("unroll")                                                        \
    for (int mf = 0; mf < 2; ++mf)                                           \
      _Pragma("unroll")                                                      \
      for (int kk = 0; kk < 2; ++kk)                                         \
        a[mf][kk] = *(const s16x8*)(&As[CUR][mf * 16 + l15][kk * 32 + lhi * 8]); \
    _Pragma("unroll")                                                        \
    for (int mf = 0; mf < 2; ++mf)                                           \
      _Pragma("unroll")                                                      \
      for (int cgi = 0; cgi < 2; ++cgi)                                      \
        _Pragma("unroll")                                                    \
        for (int kk = 0; kk < 2; ++kk)                                       \
          acc[mf][cgi] = __builtin_amdgcn_mfma_f32_16x16x32_bf16(            \
              a[mf][kk], BF[cgi * 2 + kk], acc[mf][cgi], 0, 0, 0);           \
  }

  P1X(xA, 0); P1B(bfA, 0);
  P1X(xB, 1); P1B(bfB, 1);
  for (int t = 0; t < 16; t += 2) {
    P1W(0, xA, t);
    if (t + 2 < 16) P1X(xA, t + 2);
    lds_barrier();
    P1C(0, bfA);
    if (t + 2 < 16) P1B(bfA, t + 2);
    P1W(1, xB, t + 1);
    if (t + 3 < 16) P1X(xB, t + 3);
    lds_barrier();
    P1C(1, bfB);
    if (t + 3 < 16) P1B(bfB, t + 3);
  }
#undef P1X
#undef P1B
#undef P1W
#undef P1C

  // ---- handoff: row norms + normalized Z -> Zs ----
#pragma unroll
  for (int mf = 0; mf < 2; ++mf)
#pragma unroll
    for (int r = 0; r < 4; ++r) {
      float s = acc[mf][0][r] * acc[mf][0][r] + acc[mf][1][r] * acc[mf][1][r];
#pragma unroll
      for (int o = 1; o < 16; o <<= 1) s += __shfl_xor(s, o, 16);
      if (l15 == 0) rowsq[wv][mf * 16 + lhi * 4 + r] = s;
    }
  lds_barrier();
  if (tid < 32) {
    float n2 = 0.0f;
#pragma unroll
    for (int w = 0; w < 8; ++w) n2 += rowsq[w][tid];
    invs[tid] = 1.0f / fmaxf(sqrtf(n2), 1e-12f);  // F.normalize eps
  }
  lds_barrier();
#pragma unroll
  for (int mf = 0; mf < 2; ++mf)
#pragma unroll
    for (int r = 0; r < 4; ++r) {
      int row   = mf * 16 + lhi * 4 + r;
      float inv = invs[row];
#pragma unroll
      for (int cgi = 0; cgi < 2; ++cgi)
        Zs[row][wv * 32 + cgi * 16 + l15] = f2bf(acc[mf][cgi][r] * inv);
    }
  lds_barrier();

  // ---- coalesced fragment-order store to Zb_sw ----
#pragma unroll
  for (int i = 0; i < 2; ++i) {
    int f  = wv * 2 + i;              // 0..15: rg = f>>3, kb = f&7
    int rg = f >> 3, kb = f & 7;
    s16x8 v = *(const s16x8*)(&Zs[rg * 16 + l15][kb * 32 + lhi * 8]);
    *(s16x8*)(Zb_sw + ((size_t)blockIdx.x * 16 + f) * 512 + (size_t)lane * 8) = v;
  }
}

// ---- G2: out = -sqrt(max(1 + pp - 2 * Z @ P^T, 0)) ----
// Pure streaming: NO LDS, NO barriers. 1024 blocks x 256 thr; each wave
// independently owns 32 rows x 256 protos. A-frags loaded once coalesced
// from Zb_sw (64 VGPR); B 2-deep named prefetch from Pb_sw; streamed stores.
__global__ __launch_bounds__(256, 2)
void k_g2(const unsigned short* __restrict__ Zb_sw,
          const unsigned short* __restrict__ Pb_sw,
          const float* __restrict__ pp, float* __restrict__ out) {
  const int tid  = threadIdx.x;
  const int lane = tid & 63;
  const int wv   = tid >> 6;
  const int l15  = lane & 15;
  const int lhi  = lane >> 4;

  const int rt = blockIdx.x >> 1;               // row tile [0,512): rows rt*32..+32
  const int po = (blockIdx.x & 1) * 4 + wv;     // proto oct [0,8): protos po*256..+256

  // 2-deep B prefetch (issue first, hide af-load latency under it)
  const unsigned short* pb_base =
      Pb_sw + (size_t)(po * 16) * 8 * 64 * 8 + (size_t)lane * 8;
  s16x8 brA[4], brB[4];
#define P2B(REGS, T)                                                         \
  {                                                                          \
    const int g_ = (T) >> 3, k_ = (T) & 7;                                   \
    _Pragma("unroll")                                                        \
    for (int nf = 0; nf < 4; ++nf)                                           \
      REGS[nf] = *(const s16x8*)(pb_base +                                   \
          (size_t)((g_ * 4 + nf) * 8 + k_) * 512);                           \
  }
  P2B(brA, 0);
  P2B(brB, 1);

  // A-fragments once, coalesced (16 x 1KB loads)
  s16x8 af[2][8];
#pragma unroll
  for (int mg = 0; mg < 2; ++mg)
#pragma unroll
    for (int kb = 0; kb < 8; ++kb)
      af[mg][kb] = *(const s16x8*)(Zb_sw +
          ((size_t)rt * 16 + mg * 8 + kb) * 512 + (size_t)lane * 8);

  const float* ppb = pp + po * 256;
  float* outb = out + (size_t)rt * 32 * NPROTO + po * 256;

  for (int g = 0; g < 4; ++g) {        // 64-proto chunks
    f32x4 acc2[2][4];
#pragma unroll
    for (int mf = 0; mf < 2; ++mf)
#pragma unroll
      for (int nf = 0; nf < 4; ++nf) acc2[mf][nf] = (f32x4)0.0f;

#pragma unroll
    for (int ks = 0; ks < 8; ks += 2) {
      const int t = g * 8 + ks;
#pragma unroll
      for (int mf = 0; mf < 2; ++mf)
#pragma unroll
        for (int nf = 0; nf < 4; ++nf)
          acc2[mf][nf] = __builtin_amdgcn_mfma_f32_16x16x32_bf16(
              af[mf][ks], brA[nf], acc2[mf][nf], 0, 0, 0);
      if (t + 2 < 32) P2B(brA, t + 2);
#pragma unroll
      for (int mf = 0; mf < 2; ++mf)
#pragma unroll
        for (int nf = 0; nf < 4; ++nf)
          acc2[mf][nf] = __builtin_amdgcn_mfma_f32_16x16x32_bf16(
              af[mf][ks + 1], brB[nf], acc2[mf][nf], 0, 0, 0);
      if (t + 3 < 32) P2B(brB, t + 3);
    }

    float ppv[4];
#pragma unroll
    for (int nf = 0; nf < 4; ++nf) ppv[nf] = ppb[g * 64 + nf * 16 + l15];
#pragma unroll
    for (int mf = 0; mf < 2; ++mf)
#pragma unroll
      for (int r = 0; r < 4; ++r) {
        const size_t rowoff = (size_t)(mf * 16 + lhi * 4 + r) * NPROTO;
#pragma unroll
        for (int nf = 0; nf < 4; ++nf) {
          float d2 = fmaxf(1.0f + ppv[nf] - 2.0f * acc2[mf][nf][r], 0.0f);
          outb[rowoff + g * 64 + nf * 16 + l15] = -sqrtf(d2);
        }
      }
  }
#undef P2B
}

extern "C" void kernel_launch(void* const* d_in, const int* in_sizes, int n_in,
                              void* d_out, int out_size, void* d_ws, size_t ws_size,
                              hipStream_t stream) {
  const float* X     = (const float*)d_in[0];  // [16384,1024]
  const float* mean  = (const float*)d_in[1];  // [1024]
  const float* proj  = (const float*)d_in[2];  // [1024,256]
  const float* proto = (const float*)d_in[3];  // [2048,256]
  float* out = (float*)d_out;                  // [16384,2048]

  char* ws = (char*)d_ws;
  // workspace layout (~9.5 MB total)
  size_t off = 0;
  unsigned short* projT_sw = (unsigned short*)(ws + off); off += (size_t)DIM * DP * 2;    // 512 KB
  unsigned short* Pb_sw    = (unsigned short*)(ws + off); off += (size_t)NPROTO * DP * 2; // 1 MB
  float* pp                = (float*)(ws + off);          off += (size_t)NPROTO * 4;      // 8 KB
  unsigned short* Zb_sw    = (unsigned short*)(ws + off); off += (size_t)N_ROWS * DP * 2; // 8 MB

  hipLaunchKernelGGL(k_prep, dim3(384 + NPROTO), dim3(256), 0, stream,
                     proj, proto, projT_sw, Pb_sw, pp);
  hipLaunchKernelGGL(k_g1, dim3(N_ROWS / 32), dim3(512), 0, stream,
                     X, mean, projT_sw, Zb_sw);
  hipLaunchKernelGGL(k_g2, dim3((N_ROWS / 32) * 2), dim3(256), 0, stream,
                     Zb_sw, Pb_sw, pp, out);
}